// Round 8
// baseline (199.613 us; speedup 1.0000x reference)
//
#include <hip/hip_runtime.h>

typedef unsigned short u16;
typedef __attribute__((ext_vector_type(8))) short bf16x8;   // 8 bf16 in 4 VGPRs
typedef __attribute__((ext_vector_type(4))) float f32x4;

__device__ __forceinline__ u16 f2bf(float f) {
    union { float f; unsigned u; } v; v.f = f;
    unsigned r = v.u + 0x7fffu + ((v.u >> 16) & 1u);   // RNE
    return (u16)(r >> 16);
}
__device__ __forceinline__ float bf2f(unsigned hi16) {  // hi16 = bf16 in low bits
    union { unsigned u; float f; } v; v.u = hi16 << 16; return v.f;
}

// global(16B per lane) -> LDS DMA; LDS dest = wave-uniform base + lane*16.
__device__ __forceinline__ void gload16(const u16* g, char* l) {
    __builtin_amdgcn_global_load_lds(
        (const __attribute__((address_space(1))) unsigned int*)g,
        (__attribute__((address_space(3))) unsigned int*)l, 16, 0, 0);
}

// ---------------- Kernel 1: GroupNorm stats ----------------
__global__ __launch_bounds__(256)
void k_stats(const float* __restrict__ x, float* __restrict__ mean, float* __restrict__ rstd)
{
    int bg = blockIdx.x, t = threadIdx.x;
    const float4* xp = (const float4*)(x + (size_t)bg * 16384);
    float s1 = 0.f, s2 = 0.f;
#pragma unroll
    for (int i = 0; i < 16; ++i) {
        float4 v = xp[i * 256 + t];
        s1 += v.x + v.y + v.z + v.w;
        s2 += v.x * v.x + v.y * v.y + v.z * v.z + v.w * v.w;
    }
#pragma unroll
    for (int off = 32; off >= 1; off >>= 1) {
        s1 += __shfl_xor(s1, off);
        s2 += __shfl_xor(s2, off);
    }
    __shared__ float a1[4], a2[4];
    if ((t & 63) == 0) { a1[t >> 6] = s1; a2[t >> 6] = s2; }
    __syncthreads();
    if (t == 0) {
        float t1 = a1[0] + a1[1] + a1[2] + a1[3];
        float t2 = a2[0] + a2[1] + a2[2] + a2[3];
        float mu = t1 * (1.f / 16384.f);
        float var = t2 * (1.f / 16384.f) - mu * mu;
        mean[bg] = mu;
        rstd[bg] = rsqrtf(var + 1e-5f);
    }
}

// ---------------- Kernel 2: normalize + QKV pointwise GEMM (R6 version) ----------------
// Register-blocked: thread owns 4 output channels x 16 n -> LDS reads /4.
// Q pre-scaled by 128^-0.5 * log2(e). ALL acc indices compile-time (rule #20).
__global__ __launch_bounds__(384)
void k_qkv(const float* __restrict__ x, const float* __restrict__ gn_w, const float* __restrict__ gn_b,
           const float* __restrict__ qkv_w, const float* __restrict__ qkv_b,
           const float* __restrict__ mean, const float* __restrict__ rstd,
           u16* __restrict__ Qo, u16* __restrict__ Ko, u16* __restrict__ Vo)
{
    __shared__ float xn[128][64];   // 32 KB, [channel][n-local]
    int t = threadIdx.x;
    int b = blockIdx.x >> 6;
    int n0 = (blockIdx.x & 63) << 6;

    for (int e = t; e < 8192; e += 384) {
        int c = e >> 6, nn = e & 63;
        int bg = (b << 5) + (c >> 2);
        float sc = rstd[bg] * gn_w[c];
        float sh = gn_b[c] - mean[bg] * sc;
        xn[c][nn] = x[(size_t)(b * 128 + c) * 4096 + n0 + nn] * sc + sh;
    }
    __syncthreads();

    const int og = t >> 2;          // 0..95 -> output channels og*4 .. og*4+3
    const int ng = t & 3;           // 0..3  -> n ng*16 .. ng*16+15

    float acc[4][16];
#pragma unroll
    for (int i = 0; i < 4; ++i) {
        float bs = qkv_b[og * 4 + i];
#pragma unroll
        for (int j = 0; j < 16; ++j) acc[i][j] = bs;
    }

    const float4* wr0 = (const float4*)(qkv_w + (size_t)(og * 4 + 0) * 128);
    const float4* wr1 = (const float4*)(qkv_w + (size_t)(og * 4 + 1) * 128);
    const float4* wr2 = (const float4*)(qkv_w + (size_t)(og * 4 + 2) * 128);
    const float4* wr3 = (const float4*)(qkv_w + (size_t)(og * 4 + 3) * 128);

    for (int c4 = 0; c4 < 32; ++c4) {
        float4 w0 = wr0[c4], w1 = wr1[c4], w2 = wr2[c4], w3 = wr3[c4];
#pragma unroll
        for (int cc = 0; cc < 4; ++cc) {
            int c = c4 * 4 + cc;
            float v0 = (cc == 0) ? w0.x : (cc == 1) ? w0.y : (cc == 2) ? w0.z : w0.w;
            float v1 = (cc == 0) ? w1.x : (cc == 1) ? w1.y : (cc == 2) ? w1.z : w1.w;
            float v2 = (cc == 0) ? w2.x : (cc == 1) ? w2.y : (cc == 2) ? w2.z : w2.w;
            float v3 = (cc == 0) ? w3.x : (cc == 1) ? w3.y : (cc == 2) ? w3.z : w3.w;
#pragma unroll
            for (int j4 = 0; j4 < 4; ++j4) {
                float4 xv = *(const float4*)&xn[c][ng * 16 + j4 * 4];
#pragma unroll
                for (int jj = 0; jj < 4; ++jj) {
                    float xs = (jj == 0) ? xv.x : (jj == 1) ? xv.y : (jj == 2) ? xv.z : xv.w;
                    acc[0][j4 * 4 + jj] = fmaf(xs, v0, acc[0][j4 * 4 + jj]);
                    acc[1][j4 * 4 + jj] = fmaf(xs, v1, acc[1][j4 * 4 + jj]);
                    acc[2][j4 * 4 + jj] = fmaf(xs, v2, acc[2][j4 * 4 + jj]);
                    acc[3][j4 * 4 + jj] = fmaf(xs, v3, acc[3][j4 * 4 + jj]);
                }
            }
        }
    }

    const float qscale = 0.08838834764831845f * 1.4426950408889634f;  // 128^-0.5 * log2e
    if (og < 32) {                                   // Q -> (b,n,c), pre-scaled
        size_t base = (size_t)(b * 4096 + n0 + ng * 16) * 128 + og * 4;
#pragma unroll
        for (int n = 0; n < 16; ++n) {
            uint2 pk;
            pk.x = ((unsigned)f2bf(acc[1][n] * qscale) << 16) | f2bf(acc[0][n] * qscale);
            pk.y = ((unsigned)f2bf(acc[3][n] * qscale) << 16) | f2bf(acc[2][n] * qscale);
            *(uint2*)&Qo[base + (size_t)n * 128] = pk;
        }
    } else if (og < 64) {                            // K -> (b,n,c)
        size_t base = (size_t)(b * 4096 + n0 + ng * 16) * 128 + (og - 32) * 4;
#pragma unroll
        for (int n = 0; n < 16; ++n) {
            uint2 pk;
            pk.x = ((unsigned)f2bf(acc[1][n]) << 16) | f2bf(acc[0][n]);
            pk.y = ((unsigned)f2bf(acc[3][n]) << 16) | f2bf(acc[2][n]);
            *(uint2*)&Ko[base + (size_t)n * 128] = pk;
        }
    } else {                                         // V -> (b,c,n)
#pragma unroll
        for (int i = 0; i < 4; ++i) {
            size_t base = (size_t)(b * 128 + (og - 64) * 4 + i) * 4096 + n0 + ng * 16;
            uint4 pa, pb;
            pa.x = ((unsigned)f2bf(acc[i][1]) << 16) | f2bf(acc[i][0]);
            pa.y = ((unsigned)f2bf(acc[i][3]) << 16) | f2bf(acc[i][2]);
            pa.z = ((unsigned)f2bf(acc[i][5]) << 16) | f2bf(acc[i][4]);
            pa.w = ((unsigned)f2bf(acc[i][7]) << 16) | f2bf(acc[i][6]);
            pb.x = ((unsigned)f2bf(acc[i][9]) << 16) | f2bf(acc[i][8]);
            pb.y = ((unsigned)f2bf(acc[i][11]) << 16) | f2bf(acc[i][10]);
            pb.z = ((unsigned)f2bf(acc[i][13]) << 16) | f2bf(acc[i][12]);
            pb.w = ((unsigned)f2bf(acc[i][15]) << 16) | f2bf(acc[i][14]);
            *(uint4*)&Vo[base] = pa;
            *(uint4*)&Vo[base + 8] = pb;
        }
    }
}

// ---------------- Kernel 3: flash attention, QBLK=128, KVBLK=32, 4 blocks/CU ----------------
// LDS 40 KB (K 2x8 + V 2x8 + P 8) -> 4 blocks/CU; split=8 -> grid 1024 fills them.
// Same validated 1-barrier dbuf DMA structure; swapped QK^T; exp2 softmax; defer-max.
// Swizzles (XOR involution, both sides):  K row 256B: (row&7)<<4 ;
// V/P row 64B: ((row>>1)&3)<<4.  Opart stored bf16.
__global__ __launch_bounds__(256, 4)
void k_attn(const u16* __restrict__ Qg, const u16* __restrict__ Kg, const u16* __restrict__ Vg,
            u16* __restrict__ Opart, float* __restrict__ ml,
            int split, int kvlen, int iters)
{
    __shared__ __align__(16) u16 Kl[2][32 * 128];   // 2 x 8 KB
    __shared__ __align__(16) u16 Vl[2][128 * 32];   // 2 x 8 KB
    __shared__ __align__(16) u16 Pl[4 * 32 * 32];   // 8 KB, per-wave 2 KB

    const int t = threadIdx.x;
    const int blk = blockIdx.x;
    const int half = blk % split;
    const int qt = (blk / split) & 31;
    const int b = blk / (split * 32);
    const int w = t >> 6;
    const int lane = t & 63;
    const int l15 = lane & 15;
    const int l4 = lane >> 4;
    const int q0 = qt << 7;
    const int swzK = (l15 & 7) << 4;                 // K read XOR (256B rows)
    const int swzVP = ((l15 >> 1) & 3) << 4;         // V/P read XOR (64B rows)

    bf16x8 qf[2][4];
#pragma unroll
    for (int qh = 0; qh < 2; ++qh) {
        const u16* qb = Qg + (size_t)(b * 4096 + q0 + w * 32 + qh * 16 + l15) * 128 + l4 * 8;
#pragma unroll
        for (int kc = 0; kc < 4; ++kc) qf[qh][kc] = *(const bf16x8*)(qb + kc * 32);
    }
    f32x4 oac[2][8];
#pragma unroll
    for (int qh = 0; qh < 2; ++qh)
#pragma unroll
        for (int cf = 0; cf < 8; ++cf) oac[qh][cf] = (f32x4){0.f, 0.f, 0.f, 0.f};
    float m[2] = {-__builtin_inff(), -__builtin_inff()};
    float lsum[2] = {0.f, 0.f};

    const int kv0 = half * kvlen;
    char* plw = (char*)Pl + w * 2048;

    // stage lane constants.  K: rows 8w+4i+krow, inverse-swizzled col.
    const int krow = lane >> 4;
    const int kcolA = ((lane & 15) ^ krow) * 8;          // i=0 (row&7 = krow)
    const int kcolB = ((lane & 15) ^ (krow + 4)) * 8;    // i=1 (row&7 = krow+4)
    // V: rows 32w+16i+(lane>>2), col16 = (lane&3) ^ ((lane>>3)&3)
    const int vrow = lane >> 2;
    const int vcolu = (((lane & 3) ^ ((lane >> 3) & 3))) * 8;
    const u16* KgB = Kg + (size_t)b * 4096 * 128;
    const u16* VgB = Vg + (size_t)b * 128 * 4096;

    auto STAGE = [&](int buf, int kvb) {
        char* kd = (char*)&Kl[buf][0] + w * 2048;
        char* vd = (char*)&Vl[buf][0] + w * 2048;
        const u16* kga = KgB + (size_t)(kvb + 8 * w) * 128;
        const u16* vga = VgB + kvb + (size_t)(32 * w) * 4096;
        gload16(kga + (size_t)(krow) * 128 + kcolA, kd);
        gload16(kga + (size_t)(4 + krow) * 128 + kcolB, kd + 1024);
        gload16(vga + (size_t)(vrow) * 4096 + vcolu, vd);
        gload16(vga + (size_t)(16 + vrow) * 4096 + vcolu, vd + 1024);
    };

    STAGE(0, kv0);
    __syncthreads();

    int cur = 0;
    for (int it = 0; it < iters; ++it) {
        if (it + 1 < iters) STAGE(cur ^ 1, kv0 + (it + 1) * 32);

        // S^T = K * Q^T : st[qh][mt][r] = S[q=l15][kv=mt*16+l4*4+r], mt 0..1
        const char* kb = (const char*)&Kl[cur][0];
        f32x4 st[2][2];
        __builtin_amdgcn_s_setprio(1);
#pragma unroll
        for (int mt = 0; mt < 2; ++mt) {
            f32x4 s0 = (f32x4){0.f, 0.f, 0.f, 0.f};
            f32x4 s1 = (f32x4){0.f, 0.f, 0.f, 0.f};
#pragma unroll
            for (int kc = 0; kc < 4; ++kc) {
                bf16x8 kf = *(const bf16x8*)(kb + (mt * 16 + l15) * 256 +
                                             ((kc * 64 + l4 * 16) ^ swzK));
                s0 = __builtin_amdgcn_mfma_f32_16x16x32_bf16(kf, qf[0][kc], s0, 0, 0, 0);
                s1 = __builtin_amdgcn_mfma_f32_16x16x32_bf16(kf, qf[1][kc], s1, 0, 0, 0);
            }
            st[0][mt] = s0;
            st[1][mt] = s1;
        }
        __builtin_amdgcn_s_setprio(0);

#pragma unroll
        for (int qh = 0; qh < 2; ++qh) {
            float pmax = fmaxf(fmaxf(fmaxf(st[qh][0][0], st[qh][0][1]),
                                     fmaxf(st[qh][0][2], st[qh][0][3])),
                               fmaxf(fmaxf(st[qh][1][0], st[qh][1][1]),
                                     fmaxf(st[qh][1][2], st[qh][1][3])));
            pmax = fmaxf(pmax, __shfl_xor(pmax, 16));
            pmax = fmaxf(pmax, __shfl_xor(pmax, 32));

            if (!__all(pmax - m[qh] <= 8.f)) {
                float nm = fmaxf(m[qh], pmax);
                float fr = __builtin_amdgcn_exp2f(m[qh] - nm);
                m[qh] = nm;
                lsum[qh] *= fr;
#pragma unroll
                for (int cf = 0; cf < 8; ++cf)
#pragma unroll
                    for (int r = 0; r < 4; ++r) oac[qh][cf][r] *= fr;
            }

            float rsum = 0.f;
            uint2 pw[2];
#pragma unroll
            for (int mt = 0; mt < 2; ++mt) {
                float p0 = __builtin_amdgcn_exp2f(st[qh][mt][0] - m[qh]);
                float p1 = __builtin_amdgcn_exp2f(st[qh][mt][1] - m[qh]);
                float p2 = __builtin_amdgcn_exp2f(st[qh][mt][2] - m[qh]);
                float p3 = __builtin_amdgcn_exp2f(st[qh][mt][3] - m[qh]);
                rsum += (p0 + p1) + (p2 + p3);
                pw[mt].x = ((unsigned)f2bf(p1) << 16) | f2bf(p0);
                pw[mt].y = ((unsigned)f2bf(p3) << 16) | f2bf(p2);
            }
            rsum += __shfl_xor(rsum, 16);
            rsum += __shfl_xor(rsum, 32);
            lsum[qh] += rsum;

            // P[q=qh*16+l15][kv] -> per-wave LDS, 8B swizzled writes (64B rows)
#pragma unroll
            for (int mt = 0; mt < 2; ++mt)
                *(uint2*)(plw + (qh * 16 + l15) * 64 + ((mt * 32 + l4 * 8) ^ swzVP)) = pw[mt];
        }

        // O^T += V^T * P^T  (single K=32 chunk)
        const char* vb = (const char*)&Vl[cur][0];
        bf16x8 pf0 = *(const bf16x8*)(plw + (0 * 16 + l15) * 64 + ((l4 * 16) ^ swzVP));
        bf16x8 pf1 = *(const bf16x8*)(plw + (1 * 16 + l15) * 64 + ((l4 * 16) ^ swzVP));
        __builtin_amdgcn_s_setprio(1);
#pragma unroll
        for (int cf = 0; cf < 8; ++cf) {
            bf16x8 vf = *(const bf16x8*)(vb + (cf * 16 + l15) * 64 + ((l4 * 16) ^ swzVP));
            oac[0][cf] = __builtin_amdgcn_mfma_f32_16x16x32_bf16(vf, pf0, oac[0][cf], 0, 0, 0);
            oac[1][cf] = __builtin_amdgcn_mfma_f32_16x16x32_bf16(vf, pf1, oac[1][cf], 0, 0, 0);
        }
        __builtin_amdgcn_s_setprio(0);
        __syncthreads();
        cur ^= 1;
    }

    // epilogue: lane owns q = q0+w*32+qh*16+l15; c = cf*16+l4*4+r -> bf16 uint2 stores
#pragma unroll
    for (int qh = 0; qh < 2; ++qh) {
        size_t qrow = ((size_t)half * 4 + b) * 4096 + q0 + w * 32 + qh * 16 + l15;
        u16* orow = Opart + qrow * 128;
#pragma unroll
        for (int cf = 0; cf < 8; ++cf) {
            uint2 pk;
            pk.x = ((unsigned)f2bf(oac[qh][cf][1]) << 16) | f2bf(oac[qh][cf][0]);
            pk.y = ((unsigned)f2bf(oac[qh][cf][3]) << 16) | f2bf(oac[qh][cf][2]);
            *(uint2*)&orow[cf * 16 + l4 * 4] = pk;
        }
        if (l4 == 0) {
            size_t mb = (size_t)half * 16384 + b * 4096 + q0 + w * 32 + qh * 16 + l15;
            ml[mb * 2 + 0] = m[qh];
            ml[mb * 2 + 1] = lsum[qh];
        }
    }
}

// ---------------- Kernel 4: merge split partials + out-proj + bias + residual ----------------
// R6 structure; Opart is bf16, up to 8 splits.
__global__ __launch_bounds__(256)
void k_proj(const u16* __restrict__ Opart, const float* __restrict__ ml,
            const float* __restrict__ x, const float* __restrict__ out_w,
            const float* __restrict__ out_b, float* __restrict__ out, int split)
{
    __shared__ float Ol[128][64];   // [c][n-local] merged attention output
    int t = threadIdx.x;
    int b = blockIdx.x >> 6;
    int n0 = (blockIdx.x & 63) << 6;

    for (int e = t; e < 2048; e += 256) {
        int nn = e >> 5, c4 = e & 31;
        size_t rg = (size_t)b * 4096 + n0 + nn;
        float mm = -__builtin_inff();
        float msv[8], lsv[8];
#pragma unroll
        for (int s = 0; s < 8; ++s) {
            if (s < split) {
                msv[s] = ml[((size_t)s * 16384 + rg) * 2 + 0];
                lsv[s] = ml[((size_t)s * 16384 + rg) * 2 + 1];
                mm = fmaxf(mm, msv[s]);
            } else { msv[s] = -__builtin_inff(); lsv[s] = 0.f; }
        }
        float es[8]; float L = 0.f;
#pragma unroll
        for (int s = 0; s < 8; ++s) {
            es[s] = (s < split) ? __builtin_amdgcn_exp2f(msv[s] - mm) : 0.f;
            L += lsv[s] * es[s];
        }
        float inv = 1.f / L;
        float ox = 0.f, oy = 0.f, oz = 0.f, ow = 0.f;
#pragma unroll
        for (int s = 0; s < 8; ++s) {
            if (s < split) {
                uint2 o2 = *(const uint2*)&Opart[((size_t)s * 16384 + rg) * 128 + c4 * 4];
                ox = fmaf(bf2f(o2.x & 0xffffu), es[s], ox);
                oy = fmaf(bf2f(o2.x >> 16), es[s], oy);
                oz = fmaf(bf2f(o2.y & 0xffffu), es[s], oz);
                ow = fmaf(bf2f(o2.y >> 16), es[s], ow);
            }
        }
        Ol[c4 * 4 + 0][nn] = ox * inv;
        Ol[c4 * 4 + 1][nn] = oy * inv;
        Ol[c4 * 4 + 2][nn] = oz * inv;
        Ol[c4 * 4 + 3][nn] = ow * inv;
    }
    __syncthreads();

    const int ocg = t & 31;          // oc = ocg*4 .. +3
    const int ng = t >> 5;           // n  = ng*8 .. +7

    float acc[4][8];
#pragma unroll
    for (int i = 0; i < 4; ++i) {
        float bs = out_b[ocg * 4 + i];
#pragma unroll
        for (int j = 0; j < 8; ++j) acc[i][j] = bs;
    }

    const float4* wr0 = (const float4*)(out_w + (size_t)(ocg * 4 + 0) * 128);
    const float4* wr1 = (const float4*)(out_w + (size_t)(ocg * 4 + 1) * 128);
    const float4* wr2 = (const float4*)(out_w + (size_t)(ocg * 4 + 2) * 128);
    const float4* wr3 = (const float4*)(out_w + (size_t)(ocg * 4 + 3) * 128);

    for (int c4 = 0; c4 < 32; ++c4) {
        float4 w0 = wr0[c4], w1 = wr1[c4], w2 = wr2[c4], w3 = wr3[c4];
#pragma unroll
        for (int cc = 0; cc < 4; ++cc) {
            int c = c4 * 4 + cc;
            float v0 = (cc == 0) ? w0.x : (cc == 1) ? w0.y : (cc == 2) ? w0.z : w0.w;
            float v1 = (cc == 0) ? w1.x : (cc == 1) ? w1.y : (cc == 2) ? w1.z : w1.w;
            float v2 = (cc == 0) ? w2.x : (cc == 1) ? w2.y : (cc == 2) ? w2.z : w2.w;
            float v3 = (cc == 0) ? w3.x : (cc == 1) ? w3.y : (cc == 2) ? w3.z : w3.w;
#pragma unroll
            for (int j4 = 0; j4 < 2; ++j4) {
                float4 xv = *(const float4*)&Ol[c][ng * 8 + j4 * 4];
#pragma unroll
                for (int jj = 0; jj < 4; ++jj) {
                    float xs = (jj == 0) ? xv.x : (jj == 1) ? xv.y : (jj == 2) ? xv.z : xv.w;
                    acc[0][j4 * 4 + jj] = fmaf(xs, v0, acc[0][j4 * 4 + jj]);
                    acc[1][j4 * 4 + jj] = fmaf(xs, v1, acc[1][j4 * 4 + jj]);
                    acc[2][j4 * 4 + jj] = fmaf(xs, v2, acc[2][j4 * 4 + jj]);
                    acc[3][j4 * 4 + jj] = fmaf(xs, v3, acc[3][j4 * 4 + jj]);
                }
            }
        }
    }

#pragma unroll
    for (int i = 0; i < 4; ++i) {
        size_t ob = (size_t)(b * 128 + ocg * 4 + i) * 4096 + n0 + ng * 8;
#pragma unroll
        for (int j4 = 0; j4 < 2; ++j4) {
            float4 xr = *(const float4*)&x[ob + j4 * 4];
            float4 ov;
            ov.x = acc[i][j4 * 4 + 0] + xr.x;
            ov.y = acc[i][j4 * 4 + 1] + xr.y;
            ov.z = acc[i][j4 * 4 + 2] + xr.z;
            ov.w = acc[i][j4 * 4 + 3] + xr.w;
            *(float4*)&out[ob + j4 * 4] = ov;
        }
    }
}

// ---------------- launch ----------------
extern "C" void kernel_launch(void* const* d_in, const int* in_sizes, int n_in,
                              void* d_out, int out_size, void* d_ws, size_t ws_size,
                              hipStream_t stream)
{
    const float* x     = (const float*)d_in[0];
    const float* gn_w  = (const float*)d_in[1];
    const float* gn_b  = (const float*)d_in[2];
    const float* qkv_w = (const float*)d_in[3];
    const float* qkv_b = (const float*)d_in[4];
    const float* out_w = (const float*)d_in[5];
    const float* out_b = (const float*)d_in[6];
    float* out = (float*)d_out;

    char* ws = (char*)d_ws;
    float* mean  = (float*)ws;                       // 128 f32
    float* rstd  = (float*)(ws + 512);               // 128 f32
    u16*   Q     = (u16*)(ws + 4096);                // (4,4096,128) bf16 = 4 MB
    u16*   K     = (u16*)(ws + 4198400);             // (4,4096,128) bf16 = 4 MB
    u16*   V     = (u16*)(ws + 8392704);             // (4,128,4096) bf16 = 4 MB
    float* mlb   = (float*)(ws + 12587008);          // (split,16384,2) f32 <= 1 MB
    u16*   Opart = (u16*)(ws + 13635584);            // (split,4,4096,128) bf16 <= 32 MB

    // split=8 needs 13635584 + 33554432 = 47.2 MB; fall back to 4 otherwise.
    int split = (ws_size >= (size_t)47190016) ? 8 : 4;
    int kvlen = 4096 / split;
    int iters = kvlen / 32;

    k_stats<<<128, 256, 0, stream>>>(x, mean, rstd);
    k_qkv<<<256, 384, 0, stream>>>(x, gn_w, gn_b, qkv_w, qkv_b, mean, rstd, Q, K, V);
    k_attn<<<128 * split, 256, 0, stream>>>(Q, K, V, Opart, mlb, split, kvlen, iters);
    k_proj<<<256, 256, 0, stream>>>(Opart, mlb, x, out_w, out_b, out, split);
}

// Round 9
// 125.993 us; speedup vs baseline: 1.5843x; 1.5843x over previous
//
#include <hip/hip_runtime.h>

typedef unsigned short u16;
typedef __attribute__((ext_vector_type(8))) short bf16x8;   // 8 bf16 in 4 VGPRs
typedef __attribute__((ext_vector_type(4))) float f32x4;

__device__ __forceinline__ u16 f2bf(float f) {
    union { float f; unsigned u; } v; v.f = f;
    unsigned r = v.u + 0x7fffu + ((v.u >> 16) & 1u);   // RNE
    return (u16)(r >> 16);
}

// global(16B per lane) -> LDS DMA; LDS dest = wave-uniform base + lane*16.
__device__ __forceinline__ void gload16(const u16* g, char* l) {
    __builtin_amdgcn_global_load_lds(
        (const __attribute__((address_space(1))) unsigned int*)g,
        (__attribute__((address_space(3))) unsigned int*)l, 16, 0, 0);
}

// ---------------- Kernel 1: GroupNorm stats ----------------
__global__ __launch_bounds__(256)
void k_stats(const float* __restrict__ x, float* __restrict__ mean, float* __restrict__ rstd)
{
    int bg = blockIdx.x, t = threadIdx.x;
    const float4* xp = (const float4*)(x + (size_t)bg * 16384);
    float s1 = 0.f, s2 = 0.f;
#pragma unroll
    for (int i = 0; i < 16; ++i) {
        float4 v = xp[i * 256 + t];
        s1 += v.x + v.y + v.z + v.w;
        s2 += v.x * v.x + v.y * v.y + v.z * v.z + v.w * v.w;
    }
#pragma unroll
    for (int off = 32; off >= 1; off >>= 1) {
        s1 += __shfl_xor(s1, off);
        s2 += __shfl_xor(s2, off);
    }
    __shared__ float a1[4], a2[4];
    if ((t & 63) == 0) { a1[t >> 6] = s1; a2[t >> 6] = s2; }
    __syncthreads();
    if (t == 0) {
        float t1 = a1[0] + a1[1] + a1[2] + a1[3];
        float t2 = a2[0] + a2[1] + a2[2] + a2[3];
        float mu = t1 * (1.f / 16384.f);
        float var = t2 * (1.f / 16384.f) - mu * mu;
        mean[bg] = mu;
        rstd[bg] = rsqrtf(var + 1e-5f);
    }
}

// ---------------- Kernel 2: normalize + QKV pointwise GEMM (R6, known-good) ----------------
// Register-blocked: thread owns 4 output channels x 16 n -> LDS reads /4.
// Q pre-scaled by 128^-0.5 * log2(e). ALL acc indices compile-time (rule #20).
__global__ __launch_bounds__(384)
void k_qkv(const float* __restrict__ x, const float* __restrict__ gn_w, const float* __restrict__ gn_b,
           const float* __restrict__ qkv_w, const float* __restrict__ qkv_b,
           const float* __restrict__ mean, const float* __restrict__ rstd,
           u16* __restrict__ Qo, u16* __restrict__ Ko, u16* __restrict__ Vo)
{
    __shared__ float xn[128][64];   // 32 KB, [channel][n-local]
    int t = threadIdx.x;
    int b = blockIdx.x >> 6;
    int n0 = (blockIdx.x & 63) << 6;

    for (int e = t; e < 8192; e += 384) {
        int c = e >> 6, nn = e & 63;
        int bg = (b << 5) + (c >> 2);
        float sc = rstd[bg] * gn_w[c];
        float sh = gn_b[c] - mean[bg] * sc;
        xn[c][nn] = x[(size_t)(b * 128 + c) * 4096 + n0 + nn] * sc + sh;
    }
    __syncthreads();

    const int og = t >> 2;          // 0..95 -> output channels og*4 .. og*4+3
    const int ng = t & 3;           // 0..3  -> n ng*16 .. ng*16+15

    float acc[4][16];
#pragma unroll
    for (int i = 0; i < 4; ++i) {
        float bs = qkv_b[og * 4 + i];
#pragma unroll
        for (int j = 0; j < 16; ++j) acc[i][j] = bs;
    }

    const float4* wr0 = (const float4*)(qkv_w + (size_t)(og * 4 + 0) * 128);
    const float4* wr1 = (const float4*)(qkv_w + (size_t)(og * 4 + 1) * 128);
    const float4* wr2 = (const float4*)(qkv_w + (size_t)(og * 4 + 2) * 128);
    const float4* wr3 = (const float4*)(qkv_w + (size_t)(og * 4 + 3) * 128);

    for (int c4 = 0; c4 < 32; ++c4) {
        float4 w0 = wr0[c4], w1 = wr1[c4], w2 = wr2[c4], w3 = wr3[c4];
#pragma unroll
        for (int cc = 0; cc < 4; ++cc) {
            int c = c4 * 4 + cc;
            float v0 = (cc == 0) ? w0.x : (cc == 1) ? w0.y : (cc == 2) ? w0.z : w0.w;
            float v1 = (cc == 0) ? w1.x : (cc == 1) ? w1.y : (cc == 2) ? w1.z : w1.w;
            float v2 = (cc == 0) ? w2.x : (cc == 1) ? w2.y : (cc == 2) ? w2.z : w2.w;
            float v3 = (cc == 0) ? w3.x : (cc == 1) ? w3.y : (cc == 2) ? w3.z : w3.w;
#pragma unroll
            for (int j4 = 0; j4 < 4; ++j4) {
                float4 xv = *(const float4*)&xn[c][ng * 16 + j4 * 4];
#pragma unroll
                for (int jj = 0; jj < 4; ++jj) {
                    float xs = (jj == 0) ? xv.x : (jj == 1) ? xv.y : (jj == 2) ? xv.z : xv.w;
                    acc[0][j4 * 4 + jj] = fmaf(xs, v0, acc[0][j4 * 4 + jj]);
                    acc[1][j4 * 4 + jj] = fmaf(xs, v1, acc[1][j4 * 4 + jj]);
                    acc[2][j4 * 4 + jj] = fmaf(xs, v2, acc[2][j4 * 4 + jj]);
                    acc[3][j4 * 4 + jj] = fmaf(xs, v3, acc[3][j4 * 4 + jj]);
                }
            }
        }
    }

    const float qscale = 0.08838834764831845f * 1.4426950408889634f;  // 128^-0.5 * log2e
    if (og < 32) {                                   // Q -> (b,n,c), pre-scaled
        size_t base = (size_t)(b * 4096 + n0 + ng * 16) * 128 + og * 4;
#pragma unroll
        for (int n = 0; n < 16; ++n) {
            uint2 pk;
            pk.x = ((unsigned)f2bf(acc[1][n] * qscale) << 16) | f2bf(acc[0][n] * qscale);
            pk.y = ((unsigned)f2bf(acc[3][n] * qscale) << 16) | f2bf(acc[2][n] * qscale);
            *(uint2*)&Qo[base + (size_t)n * 128] = pk;
        }
    } else if (og < 64) {                            // K -> (b,n,c)
        size_t base = (size_t)(b * 4096 + n0 + ng * 16) * 128 + (og - 32) * 4;
#pragma unroll
        for (int n = 0; n < 16; ++n) {
            uint2 pk;
            pk.x = ((unsigned)f2bf(acc[1][n]) << 16) | f2bf(acc[0][n]);
            pk.y = ((unsigned)f2bf(acc[3][n]) << 16) | f2bf(acc[2][n]);
            *(uint2*)&Ko[base + (size_t)n * 128] = pk;
        }
    } else {                                         // V -> (b,c,n)
#pragma unroll
        for (int i = 0; i < 4; ++i) {
            size_t base = (size_t)(b * 128 + (og - 64) * 4 + i) * 4096 + n0 + ng * 16;
            uint4 pa, pb;
            pa.x = ((unsigned)f2bf(acc[i][1]) << 16) | f2bf(acc[i][0]);
            pa.y = ((unsigned)f2bf(acc[i][3]) << 16) | f2bf(acc[i][2]);
            pa.z = ((unsigned)f2bf(acc[i][5]) << 16) | f2bf(acc[i][4]);
            pa.w = ((unsigned)f2bf(acc[i][7]) << 16) | f2bf(acc[i][6]);
            pb.x = ((unsigned)f2bf(acc[i][9]) << 16) | f2bf(acc[i][8]);
            pb.y = ((unsigned)f2bf(acc[i][11]) << 16) | f2bf(acc[i][10]);
            pb.z = ((unsigned)f2bf(acc[i][13]) << 16) | f2bf(acc[i][12]);
            pb.w = ((unsigned)f2bf(acc[i][15]) << 16) | f2bf(acc[i][14]);
            *(uint4*)&Vo[base] = pa;
            *(uint4*)&Vo[base + 8] = pb;
        }
    }
}

// ---------------- Kernel 3: flash attention, QBLK=128 (R6 structure) ----------------
// ONE change vs R6: XCD-aware block decode (split==4 path). XCD x hosts combos
// {x, x+8} where combo c = b*4+half -> per-XCD KV working set = 4 MB = L2 size.
// Everything else identical to the validated 60 us R6 kernel.
__global__ __launch_bounds__(256, 2)
void k_attn(const u16* __restrict__ Qg, const u16* __restrict__ Kg, const u16* __restrict__ Vg,
            float* __restrict__ Opart, float* __restrict__ ml,
            int split, int kvlen, int iters)
{
    __shared__ __align__(16) u16 Kl[2][64 * 128];   // 2 x 16 KB, swizzled
    __shared__ __align__(16) u16 Vl[2][128 * 64];   // 2 x 16 KB, swizzled
    __shared__ __align__(16) u16 Pl[4 * 32 * 64];   // 16 KB, per-wave 4 KB

    const int t = threadIdx.x;
    const int blk = blockIdx.x;
    int half, qt, b;
    if (split == 4) {
        // bijective XCD-grouping remap (grid 512, 64 blocks/XCD, 512%8==0)
        int idx = blk >> 3;                  // 0..63
        qt = idx & 31;
        int c = (blk & 7) + ((idx >> 5) << 3);   // combo 0..15 = b*4+half
        b = c >> 2;
        half = c & 3;
    } else {
        half = blk % split;
        qt = (blk / split) & 31;
        b = blk / (split * 32);
    }
    const int w = t >> 6;
    const int lane = t & 63;
    const int l15 = lane & 15;
    const int l4 = lane >> 4;
    const int q0 = qt << 7;
    const int swz = (l15 & 7) << 4;               // read-side XOR (bytes)

    bf16x8 qf[2][4];
#pragma unroll
    for (int qh = 0; qh < 2; ++qh) {
        const u16* qb = Qg + (size_t)(b * 4096 + q0 + w * 32 + qh * 16 + l15) * 128 + l4 * 8;
#pragma unroll
        for (int kc = 0; kc < 4; ++kc) qf[qh][kc] = *(const bf16x8*)(qb + kc * 32);
    }
    f32x4 oac[2][8];
#pragma unroll
    for (int qh = 0; qh < 2; ++qh)
#pragma unroll
        for (int cf = 0; cf < 8; ++cf) oac[qh][cf] = (f32x4){0.f, 0.f, 0.f, 0.f};
    float m[2] = {-__builtin_inff(), -__builtin_inff()};
    float lsum[2] = {0.f, 0.f};

    const int kv0 = half * kvlen;
    char* plw = (char*)Pl + w * 4096;

    const int krow = lane >> 4;
    const int vrow = lane >> 3;
    const int kcolA = ((lane & 15) ^ krow) * 8;
    const int kcolB = ((lane & 15) ^ (krow + 4)) * 8;
    const int vcol  = ((lane & 7) ^ (vrow & 7)) * 8;
    const u16* KgB = Kg + (size_t)b * 4096 * 128;
    const u16* VgB = Vg + (size_t)b * 128 * 4096;

    auto STAGE = [&](int buf, int kvb) {
        char* kd = (char*)&Kl[buf][0] + w * 4096;
        char* vd = (char*)&Vl[buf][0] + w * 4096;
        const u16* kga = KgB + (size_t)(kvb + 16 * w) * 128;
        const u16* vga = VgB + kvb + (size_t)(32 * w) * 4096;
#pragma unroll
        for (int i = 0; i < 4; ++i) {
            gload16(kga + (size_t)(4 * i + krow) * 128 + ((i & 1) ? kcolB : kcolA),
                    kd + i * 1024);
            gload16(vga + (size_t)(8 * i + vrow) * 4096 + vcol,
                    vd + i * 1024);
        }
    };

    STAGE(0, kv0);
    __syncthreads();

    int cur = 0;
    for (int it = 0; it < iters; ++it) {
        if (it + 1 < iters) STAGE(cur ^ 1, kv0 + (it + 1) * 64);

        const char* kb = (const char*)&Kl[cur][0];
        f32x4 st[2][4];
        __builtin_amdgcn_s_setprio(1);
#pragma unroll
        for (int mt = 0; mt < 4; ++mt) {
            f32x4 s0 = (f32x4){0.f, 0.f, 0.f, 0.f};
            f32x4 s1 = (f32x4){0.f, 0.f, 0.f, 0.f};
#pragma unroll
            for (int kc = 0; kc < 4; ++kc) {
                bf16x8 kf = *(const bf16x8*)(kb + (mt * 16 + l15) * 256 +
                                             ((kc * 64 + l4 * 16) ^ swz));
                s0 = __builtin_amdgcn_mfma_f32_16x16x32_bf16(kf, qf[0][kc], s0, 0, 0, 0);
                s1 = __builtin_amdgcn_mfma_f32_16x16x32_bf16(kf, qf[1][kc], s1, 0, 0, 0);
            }
            st[0][mt] = s0;
            st[1][mt] = s1;
        }
        __builtin_amdgcn_s_setprio(0);

#pragma unroll
        for (int qh = 0; qh < 2; ++qh) {
            float pmax = -__builtin_inff();
#pragma unroll
            for (int mt = 0; mt < 4; ++mt)
                pmax = fmaxf(pmax, fmaxf(fmaxf(st[qh][mt][0], st[qh][mt][1]),
                                         fmaxf(st[qh][mt][2], st[qh][mt][3])));
            pmax = fmaxf(pmax, __shfl_xor(pmax, 16));
            pmax = fmaxf(pmax, __shfl_xor(pmax, 32));

            if (!__all(pmax - m[qh] <= 8.f)) {
                float nm = fmaxf(m[qh], pmax);
                float fr = __builtin_amdgcn_exp2f(m[qh] - nm);
                m[qh] = nm;
                lsum[qh] *= fr;
#pragma unroll
                for (int cf = 0; cf < 8; ++cf)
#pragma unroll
                    for (int r = 0; r < 4; ++r) oac[qh][cf][r] *= fr;
            }

            float rsum = 0.f;
            uint2 pw[4];
#pragma unroll
            for (int mt = 0; mt < 4; ++mt) {
                float p0 = __builtin_amdgcn_exp2f(st[qh][mt][0] - m[qh]);
                float p1 = __builtin_amdgcn_exp2f(st[qh][mt][1] - m[qh]);
                float p2 = __builtin_amdgcn_exp2f(st[qh][mt][2] - m[qh]);
                float p3 = __builtin_amdgcn_exp2f(st[qh][mt][3] - m[qh]);
                rsum += (p0 + p1) + (p2 + p3);
                pw[mt].x = ((unsigned)f2bf(p1) << 16) | f2bf(p0);
                pw[mt].y = ((unsigned)f2bf(p3) << 16) | f2bf(p2);
            }
            rsum += __shfl_xor(rsum, 16);
            rsum += __shfl_xor(rsum, 32);
            lsum[qh] += rsum;

#pragma unroll
            for (int mt = 0; mt < 4; ++mt)
                *(uint2*)(plw + (qh * 16 + l15) * 128 + ((mt * 32 + l4 * 8) ^ swz)) = pw[mt];
        }
        asm volatile("s_waitcnt lgkmcnt(0)" ::: "memory");
        __builtin_amdgcn_sched_barrier(0);

        const char* vb = (const char*)&Vl[cur][0];
        __builtin_amdgcn_s_setprio(1);
#pragma unroll
        for (int kc2 = 0; kc2 < 2; ++kc2) {
            bf16x8 pf0 = *(const bf16x8*)(plw + (0 * 16 + l15) * 128 + ((kc2 * 64 + l4 * 16) ^ swz));
            bf16x8 pf1 = *(const bf16x8*)(plw + (1 * 16 + l15) * 128 + ((kc2 * 64 + l4 * 16) ^ swz));
#pragma unroll
            for (int cf = 0; cf < 8; ++cf) {
                bf16x8 vf = *(const bf16x8*)(vb + (cf * 16 + l15) * 128 +
                                             ((kc2 * 64 + l4 * 16) ^ swz));
                oac[0][cf] = __builtin_amdgcn_mfma_f32_16x16x32_bf16(vf, pf0, oac[0][cf], 0, 0, 0);
                oac[1][cf] = __builtin_amdgcn_mfma_f32_16x16x32_bf16(vf, pf1, oac[1][cf], 0, 0, 0);
            }
        }
        __builtin_amdgcn_s_setprio(0);
        __syncthreads();
        cur ^= 1;
    }

#pragma unroll
    for (int qh = 0; qh < 2; ++qh) {
        size_t qrow = ((size_t)half * 4 + b) * 4096 + q0 + w * 32 + qh * 16 + l15;
        float* orow = Opart + qrow * 128;
#pragma unroll
        for (int cf = 0; cf < 8; ++cf) {
            float4 v;
            v.x = oac[qh][cf][0]; v.y = oac[qh][cf][1];
            v.z = oac[qh][cf][2]; v.w = oac[qh][cf][3];
            *(float4*)&orow[cf * 16 + l4 * 4] = v;
        }
        if (l4 == 0) {
            size_t mb = (size_t)half * 16384 + b * 4096 + q0 + w * 32 + qh * 16 + l15;
            ml[mb * 2 + 0] = m[qh];
            ml[mb * 2 + 1] = lsum[qh];
        }
    }
}

// ---------------- Kernel 4: merge split partials + out-proj + bias + residual (R6) ----------------
__global__ __launch_bounds__(256)
void k_proj(const float* __restrict__ Opart, const float* __restrict__ ml,
            const float* __restrict__ x, const float* __restrict__ out_w,
            const float* __restrict__ out_b, float* __restrict__ out, int split)
{
    __shared__ float Ol[128][64];   // [c][n-local] merged attention output
    int t = threadIdx.x;
    int b = blockIdx.x >> 6;
    int n0 = (blockIdx.x & 63) << 6;

    for (int e = t; e < 2048; e += 256) {
        int nn = e >> 5, c4 = e & 31;
        size_t rg = (size_t)b * 4096 + n0 + nn;
        float msv[4], lsv[4];
#pragma unroll
        for (int s = 0; s < 4; ++s) {
            if (s < split) {
                msv[s] = ml[((size_t)s * 16384 + rg) * 2 + 0];
                lsv[s] = ml[((size_t)s * 16384 + rg) * 2 + 1];
            } else { msv[s] = -__builtin_inff(); lsv[s] = 0.f; }
        }
        float mm = fmaxf(fmaxf(msv[0], msv[1]), fmaxf(msv[2], msv[3]));
        float es[4]; float L = 0.f;
#pragma unroll
        for (int s = 0; s < 4; ++s) {
            es[s] = (s < split) ? __builtin_amdgcn_exp2f(msv[s] - mm) : 0.f;
            L += lsv[s] * es[s];
        }
        float inv = 1.f / L;
        float ox = 0.f, oy = 0.f, oz = 0.f, ow = 0.f;
#pragma unroll
        for (int s = 0; s < 4; ++s) {
            if (s < split) {
                float4 o4 = *(const float4*)&Opart[((size_t)s * 16384 + rg) * 128 + c4 * 4];
                ox = fmaf(o4.x, es[s], ox); oy = fmaf(o4.y, es[s], oy);
                oz = fmaf(o4.z, es[s], oz); ow = fmaf(o4.w, es[s], ow);
            }
        }
        Ol[c4 * 4 + 0][nn] = ox * inv;
        Ol[c4 * 4 + 1][nn] = oy * inv;
        Ol[c4 * 4 + 2][nn] = oz * inv;
        Ol[c4 * 4 + 3][nn] = ow * inv;
    }
    __syncthreads();

    const int ocg = t & 31;          // oc = ocg*4 .. +3
    const int ng = t >> 5;           // n  = ng*8 .. +7

    float acc[4][8];
#pragma unroll
    for (int i = 0; i < 4; ++i) {
        float bs = out_b[ocg * 4 + i];
#pragma unroll
        for (int j = 0; j < 8; ++j) acc[i][j] = bs;
    }

    const float4* wr0 = (const float4*)(out_w + (size_t)(ocg * 4 + 0) * 128);
    const float4* wr1 = (const float4*)(out_w + (size_t)(ocg * 4 + 1) * 128);
    const float4* wr2 = (const float4*)(out_w + (size_t)(ocg * 4 + 2) * 128);
    const float4* wr3 = (const float4*)(out_w + (size_t)(ocg * 4 + 3) * 128);

    for (int c4 = 0; c4 < 32; ++c4) {
        float4 w0 = wr0[c4], w1 = wr1[c4], w2 = wr2[c4], w3 = wr3[c4];
#pragma unroll
        for (int cc = 0; cc < 4; ++cc) {
            int c = c4 * 4 + cc;
            float v0 = (cc == 0) ? w0.x : (cc == 1) ? w0.y : (cc == 2) ? w0.z : w0.w;
            float v1 = (cc == 0) ? w1.x : (cc == 1) ? w1.y : (cc == 2) ? w1.z : w1.w;
            float v2 = (cc == 0) ? w2.x : (cc == 1) ? w2.y : (cc == 2) ? w2.z : w2.w;
            float v3 = (cc == 0) ? w3.x : (cc == 1) ? w3.y : (cc == 2) ? w3.z : w3.w;
#pragma unroll
            for (int j4 = 0; j4 < 2; ++j4) {
                float4 xv = *(const float4*)&Ol[c][ng * 8 + j4 * 4];
#pragma unroll
                for (int jj = 0; jj < 4; ++jj) {
                    float xs = (jj == 0) ? xv.x : (jj == 1) ? xv.y : (jj == 2) ? xv.z : xv.w;
                    acc[0][j4 * 4 + jj] = fmaf(xs, v0, acc[0][j4 * 4 + jj]);
                    acc[1][j4 * 4 + jj] = fmaf(xs, v1, acc[1][j4 * 4 + jj]);
                    acc[2][j4 * 4 + jj] = fmaf(xs, v2, acc[2][j4 * 4 + jj]);
                    acc[3][j4 * 4 + jj] = fmaf(xs, v3, acc[3][j4 * 4 + jj]);
                }
            }
        }
    }

#pragma unroll
    for (int i = 0; i < 4; ++i) {
        size_t ob = (size_t)(b * 128 + ocg * 4 + i) * 4096 + n0 + ng * 8;
#pragma unroll
        for (int j4 = 0; j4 < 2; ++j4) {
            float4 xr = *(const float4*)&x[ob + j4 * 4];
            float4 ov;
            ov.x = acc[i][j4 * 4 + 0] + xr.x;
            ov.y = acc[i][j4 * 4 + 1] + xr.y;
            ov.z = acc[i][j4 * 4 + 2] + xr.z;
            ov.w = acc[i][j4 * 4 + 3] + xr.w;
            *(float4*)&out[ob + j4 * 4] = ov;
        }
    }
}

// ---------------- launch ----------------
extern "C" void kernel_launch(void* const* d_in, const int* in_sizes, int n_in,
                              void* d_out, int out_size, void* d_ws, size_t ws_size,
                              hipStream_t stream)
{
    const float* x     = (const float*)d_in[0];
    const float* gn_w  = (const float*)d_in[1];
    const float* gn_b  = (const float*)d_in[2];
    const float* qkv_w = (const float*)d_in[3];
    const float* qkv_b = (const float*)d_in[4];
    const float* out_w = (const float*)d_in[5];
    const float* out_b = (const float*)d_in[6];
    float* out = (float*)d_out;

    char* ws = (char*)d_ws;
    float* mean  = (float*)ws;                       // 128 f32
    float* rstd  = (float*)(ws + 512);               // 128 f32
    u16*   Q     = (u16*)(ws + 4096);                // (4,4096,128) bf16 = 4 MB
    u16*   K     = (u16*)(ws + 4198400);             // (4,4096,128) bf16 = 4 MB
    u16*   V     = (u16*)(ws + 8392704);             // (4,128,4096) bf16 = 4 MB
    float* mlb   = (float*)(ws + 12587008);          // (split,16384,2) f32 <= 512 KB
    float* Opart = (float*)(ws + 13111296);          // (split,4,4096,128) f32 <= 32 MB

    int split = (ws_size >= (size_t)46700000) ? 4 : 2;
    int kvlen = 4096 / split;
    int iters = kvlen / 64;

    k_stats<<<128, 256, 0, stream>>>(x, mean, rstd);
    k_qkv<<<256, 384, 0, stream>>>(x, gn_w, gn_b, qkv_w, qkv_b, mean, rstd, Q, K, V);
    k_attn<<<128 * split, 256, 0, stream>>>(Q, K, V, Opart, mlb, split, kvlen, iters);
    k_proj<<<256, 256, 0, stream>>>(Opart, mlb, x, out_w, out_b, out, split);
}